// Round 11
// baseline (344.055 us; speedup 1.0000x reference)
//
#include <hip/hip_runtime.h>
#include <hip/hip_bf16.h>

#define NPOS  131072     // B*H*W = 32*64*64
#define NEMB  1024
#define DIM   64
#define NELEM 8388608    // NPOS*DIM
#define HW    4096

// ws element offsets (4-byte units)
#define EMBF32_OFF 0          // float[65536]
#define EE_OFF     65536      // float[1024]  (np-pairwise f32 ||E||^2)
#define EE24_OFF   66560      // float[1024]  (ee * 2^24)
#define EHI_OFF    67584      // ushort[65536] bf16(E * 2^12)  (32768 ints)
#define IDX_OFF    100352     // int[131072]
#define CNT_OFF    231424     // int (pair-refine count)
#define FLAG_OFF   231425     // int: b0 z-bf16-storage, b1 e-bf16-storage, b2 z-bf16-valued, b3 e-bf16-valued
#define CNT2_OFF   231426     // int (full-refine count)
#define CNT3_OFF   231427     // int (k3 done-counter)
#define ACC_OFF    231428     // double (byte 925712, 8-aligned)
#define WL_OFF     231430     // int[32768] pair npos
#define WLP_OFF    264198     // int[32768] packed (i1<<10)|i2
#define WL2_OFF    296966     // int[8192] full npos (ends 305158)
#define CAPP       32768
#define CAPF       8192
#define W24        3355       // 2e-4 * 2^24: >20 sigma vs z*Elo screen error + np jitter
#define KSCALE     16777216.0f
#define KCLAMP     2080374.0f // 0.124 * 2^24 (keeps |key| < 2^31 after <<10)
#define SCA        -8192.0f   // -2^13 on A (z)
#define SCB        4096.0f    // +2^12 on B (E) -> product -2^25 * zE

typedef short bf16x8 __attribute__((ext_vector_type(8)));
typedef float f32x4  __attribute__((ext_vector_type(4)));

__device__ __forceinline__ float b2f(unsigned short u) {
  return __uint_as_float((unsigned)u << 16);
}
__device__ __forceinline__ unsigned short f2b_rne(float f) {
  unsigned u = __float_as_uint(f);
  unsigned r = u + 0x7FFF + ((u >> 16) & 1);
  return (unsigned short)(r >> 16);
}
__device__ __forceinline__ void kins(int& K1, int& K2, int& K3, int key) {
  int nk1 = min(K1, key);
  int nk2 = max(K1, min(K2, key));      // med3 given K1<=K2
  int nk3 = min(K3, max(K2, key));
  K1 = nk1; K2 = nk2; K3 = nk3;
}

// ---- dtype/value sniffer + counter init ----
__global__ void k_detect(const unsigned int* __restrict__ z,
                         const unsigned int* __restrict__ emb,
                         int* __restrict__ wsI) {
  int lane = threadIdx.x;  // 64 threads
  unsigned short vz = ((const unsigned short*)z)[2 * lane];
  unsigned short ve = ((const unsigned short*)emb)[2 * lane];
  int ez = (vz >> 7) & 0xFF;
  int ee = (ve >> 7) & 0xFF;
  unsigned long long mz = __ballot(ez >= 121 && ez <= 131);
  unsigned long long me = __ballot(ee >= 96 && ee <= 118);
  unsigned zu = z[lane * 65536];
  unsigned eu = emb[lane * 500];
  unsigned long long mzl = __ballot((zu & 0xFFFFu) == 0);
  unsigned long long mel = __ballot((eu & 0xFFFFu) == 0);
  if (lane == 0) {
    int f = 0;
    if (__popcll(mz) >= 32) f |= 1;
    if (__popcll(me) >= 32) f |= 2;
    if (mzl == ~0ull) f |= 4;
    if (mel == ~0ull) f |= 8;
    wsI[FLAG_OFF] = f;
    wsI[CNT_OFF] = 0;
    wsI[CNT2_OFF] = 0;
    wsI[CNT3_OFF] = 0;
    *(double*)(wsI + ACC_OFF) = 0.0;
  }
}

// ---- emb prep: wave per row; f32 + scaled-bf16-hi + np-exact ||E||^2 ----
__global__ __launch_bounds__(256) void k0_prep(const void* __restrict__ emb,
                                               float* __restrict__ ws) {
  int flag_e = ((const int*)ws)[FLAG_OFF] & 2;
  unsigned short* EHI = (unsigned short*)(ws + EHI_OFF);
  int wv = threadIdx.x >> 6, lane = threadIdx.x & 63;
  int e = blockIdx.x * 4 + wv;           // 256 blocks x 4 waves = 1024 rows
  float v = flag_e ? b2f(((const unsigned short*)emb)[e * DIM + lane])
                   : ((const float*)emb)[e * DIM + lane];
  ws[EMBF32_OFF + e * DIM + lane] = v;
  EHI[e * DIM + lane] = f2b_rne(__fmul_rn(v, SCB));  // bf16(E*2^12), exact scale
  float sq = __fmul_rn(v, v);
  float r[8];
#pragma unroll
  for (int q = 0; q < 8; ++q) r[q] = __shfl(sq, q, 64);
#pragma unroll
  for (int t = 1; t < 8; ++t)
#pragma unroll
    for (int q = 0; q < 8; ++q)
      r[q] = __fadd_rn(r[q], __shfl(sq, t * 8 + q, 64));
  float lft = __fadd_rn(__fadd_rn(r[0], r[1]), __fadd_rn(r[2], r[3]));
  float rgt = __fadd_rn(__fadd_rn(r[4], r[5]), __fadd_rn(r[6], r[7]));
  float eev = __fadd_rn(lft, rgt);
  if (lane == 0) {
    ws[EE_OFF + e] = eev;
    ws[EE24_OFF + e] = __fmul_rn(eev, KSCALE);
  }
}

// ---- unified MFMA screening: (zhi+zlo) x Ehi; Ehi-only LDS (36 KB, 4 blk/CU) ----
__global__ __launch_bounds__(256, 4) void k1_screen(const void* __restrict__ zv,
                                                    const float* __restrict__ ws,
                                                    int* __restrict__ idx,
                                                    int* __restrict__ cnt,
                                                    int* __restrict__ cnt2,
                                                    int* __restrict__ wl,
                                                    int* __restrict__ wlp,
                                                    int* __restrict__ wl2) {
  int flag = ((const int*)ws)[FLAG_OFF];
  const bool zsplit = !(flag & 5);       // z has a nonzero lo part
  __shared__ uint4 sE[2048];             // 32 KB: 256 rows x 8 chunks, XOR-swizzled
  __shared__ float see24[1024];          // 4 KB
  int tid = threadIdx.x;
  for (int i = tid; i < 1024; i += 256) see24[i] = ws[EE24_OFF + i];

  int w = tid >> 6, lane = tid & 63;
  int mcol = lane & 15, g = lane >> 4;
  int posb = blockIdx.x * 128 + w * 32;
  int b = posb >> 12, hwb = posb & 4095;

  // A-frags scaled by -2^13: lane holds z[pos=posb+T*16+mcol][k=s*32+g*8+j]
  bf16x8 Ahi[2][2], Alo[2][2];
#pragma unroll
  for (int T = 0; T < 2; ++T) {
    int col = hwb + T * 16 + mcol;
#pragma unroll
    for (int s = 0; s < 2; ++s)
#pragma unroll
      for (int j = 0; j < 8; ++j) {
        size_t off = (size_t)b * 262144 + (size_t)(s * 32 + g * 8 + j) * 4096 + col;
        float v = (flag & 1) ? b2f(((const unsigned short*)zv)[off])
                             : ((const float*)zv)[off];
        float sv = __fmul_rn(v, SCA);            // exact pow2 scale
        unsigned short h = f2b_rne(sv);
        Ahi[T][s][j] = (short)h;
        Alo[T][s][j] = zsplit ? (short)f2b_rne(__fsub_rn(sv, b2f(h))) : (short)0;
      }
  }

  int K1[8], K2[8], K3[8];
#pragma unroll
  for (int s = 0; s < 8; ++s) { K1[s] = 0x7FFFFFFF; K2[s] = 0x7FFFFFFF; K3[s] = 0x7FFFFFFF; }

  const uint4* EHIg = (const uint4*)(ws + EHI_OFF);
  const f32x4 zero = {0.f, 0.f, 0.f, 0.f};

  for (int p = 0; p < 4; ++p) {
    __syncthreads();
    for (int i = tid; i < 2048; i += 256) {
      int lr = i >> 3, c = i & 7;
      sE[lr * 8 + (c ^ (lr & 7))] = EHIg[p * 2048 + i];
    }
    __syncthreads();
    for (int nt = 0; nt < 16; ++nt) {
      int lr = nt * 16 + mcol;
      int row = p * 256 + lr;
      int sw = mcol & 7;
      bf16x8 h0 = *(const bf16x8*)&sE[lr * 8 + (g ^ sw)];
      bf16x8 h1 = *(const bf16x8*)&sE[lr * 8 + ((4 + g) ^ sw)];
      float ev = see24[row];
      f32x4 cin = {ev, ev, ev, ev};       // ee*2^24 folded into C-operand
#pragma unroll
      for (int T = 0; T < 2; ++T) {
        f32x4 acc = __builtin_amdgcn_mfma_f32_16x16x32_bf16(Ahi[T][0], h0, cin, 0, 0, 0);
        acc = __builtin_amdgcn_mfma_f32_16x16x32_bf16(Ahi[T][1], h1, acc, 0, 0, 0);
        f32x4 accb;
        if (zsplit) {
          accb = __builtin_amdgcn_mfma_f32_16x16x32_bf16(Alo[T][0], h0, zero, 0, 0, 0);
          accb = __builtin_amdgcn_mfma_f32_16x16x32_bf16(Alo[T][1], h1, accb, 0, 0, 0);
        }
#pragma unroll
        for (int r = 0; r < 4; ++r) {
          int s = T * 4 + r;
          float xf = zsplit ? __fadd_rn(acc[r], accb[r]) : acc[r];
          xf = fminf(fmaxf(xf, -KCLAMP), KCLAMP);
          kins(K1[s], K2[s], K3[s], ((int)xf << 10) | row);
        }
      }
    }
  }
#pragma unroll
  for (int d = 1; d < 16; d <<= 1) {
#pragma unroll
    for (int s = 0; s < 8; ++s) {
      int o1 = __shfl_xor(K1[s], d, 64);
      int o2 = __shfl_xor(K2[s], d, 64);
      int o3 = __shfl_xor(K3[s], d, 64);
      kins(K1[s], K2[s], K3[s], o1);
      kins(K1[s], K2[s], K3[s], o2);
      kins(K1[s], K2[s], K3[s], o3);
    }
  }
  if (mcol < 4) {
#pragma unroll
    for (int T = 0; T < 2; ++T) {
      int s = T * 4 + mcol;
      int npos = posb + T * 16 + g * 4 + mcol;
      int i1 = K1[s] & 1023;
      idx[npos] = i1;
      int v1 = K1[s] >> 10, v2 = K2[s] >> 10, v3 = K3[s] >> 10;
      if (v2 - v1 < W24) {
        if (v3 - v1 < W24) {
          int slot = atomicAdd(cnt2, 1);
          if (slot < CAPF) wl2[slot] = npos;
        } else {
          int slot = atomicAdd(cnt, 1);
          if (slot < CAPP) { wl[slot] = npos; wlp[slot] = (i1 << 10) | (K2[s] & 1023); }
        }
      }
    }
  }
}

// ---- combined refine: blocks [0,128) pair, [128,384) full scan ----
__global__ __launch_bounds__(256) void k2_refine(const void* __restrict__ zv,
                                                 const float* __restrict__ ws,
                                                 const int* __restrict__ cntp,
                                                 const int* __restrict__ cnt2p,
                                                 const int* __restrict__ wl,
                                                 const int* __restrict__ wlp,
                                                 const int* __restrict__ wl2,
                                                 int* __restrict__ idx) {
  int flag_z = ((const int*)ws)[FLAG_OFF] & 1;
  const float* Ef = ws + EMBF32_OFF;
  const float* ee = ws + EE_OFF;
  if (blockIdx.x < 128) {
    // ---- pair: exact np-f32 d-hat for {i1,i2}; one wave per entry ----
    int mcnt = *cntp;
    if (mcnt > CAPP) mcnt = CAPP;
    int lane = threadIdx.x & 63;
    int gw = (blockIdx.x * 256 + threadIdx.x) >> 6;
    for (int j = gw; j < mcnt; j += 512) {
      int n = wl[j];
      int pk = wlp[j];
      int ea = pk >> 10, eb = pk & 1023;
      int b = n >> 12, hw = n & 4095;
      size_t off = (size_t)b * 262144 + (size_t)lane * 4096 + hw;
      float zk = flag_z ? b2f(((const unsigned short*)zv)[off])
                        : ((const float*)zv)[off];
      float sq = __fmul_rn(zk, zk);
      float r[8];
#pragma unroll
      for (int q = 0; q < 8; ++q) r[q] = __shfl(sq, q, 64);
#pragma unroll
      for (int t = 1; t < 8; ++t)
#pragma unroll
        for (int q = 0; q < 8; ++q)
          r[q] = __fadd_rn(r[q], __shfl(sq, t * 8 + q, 64));
      float lft = __fadd_rn(__fadd_rn(r[0], r[1]), __fadd_rn(r[2], r[3]));
      float rgt = __fadd_rn(__fadd_rn(r[4], r[5]), __fadd_rn(r[6], r[7]));
      float t1 = __fadd_rn(lft, rgt);
      double pa = (double)Ef[ea * DIM + lane] * (double)zk;
      double pb = (double)Ef[eb * DIM + lane] * (double)zk;
#pragma unroll
      for (int d = 32; d > 0; d >>= 1) {
        pa += __shfl_xor(pa, d, 64);
        pb += __shfl_xor(pb, d, 64);
      }
      float da = __fadd_rn(__fsub_rn(t1, __fmul_rn(2.0f, (float)pa)), ee[ea]);
      float db = __fadd_rn(__fsub_rn(t1, __fmul_rn(2.0f, (float)pb)), ee[eb]);
      int win = (db < da) ? eb : ((da < db) ? ea : (ea < eb ? ea : eb));
      if (lane == 0) idx[n] = win;
    }
  } else {
    // ---- full scan with np-exact f32 ----
    __shared__ float zs[DIM];
    __shared__ float t1s;
    __shared__ float bval[256];
    __shared__ int bidx[256];
    int m = *cnt2p;
    if (m > CAPF) m = CAPF;
    for (int j = (int)blockIdx.x - 128; j < m; j += 256) {
      int n = wl2[j];
      __syncthreads();
      if (threadIdx.x < DIM) {
        int b = n >> 12, hw = n & 4095;
        size_t off = (size_t)b * (DIM * HW) + (size_t)threadIdx.x * HW + hw;
        zs[threadIdx.x] = flag_z ? b2f(((const unsigned short*)zv)[off])
                                 : ((const float*)zv)[off];
      }
      __syncthreads();
      if (threadIdx.x == 0) {
        float sq[DIM];
        for (int k = 0; k < DIM; ++k) sq[k] = __fmul_rn(zs[k], zs[k]);
        float r0 = sq[0], r1 = sq[1], r2 = sq[2], r3 = sq[3];
        float r4 = sq[4], r5 = sq[5], r6 = sq[6], r7 = sq[7];
        for (int i = 8; i < 64; i += 8) {
          r0 = __fadd_rn(r0, sq[i]);     r1 = __fadd_rn(r1, sq[i + 1]);
          r2 = __fadd_rn(r2, sq[i + 2]); r3 = __fadd_rn(r3, sq[i + 3]);
          r4 = __fadd_rn(r4, sq[i + 4]); r5 = __fadd_rn(r5, sq[i + 5]);
          r6 = __fadd_rn(r6, sq[i + 6]); r7 = __fadd_rn(r7, sq[i + 7]);
        }
        float l = __fadd_rn(__fadd_rn(r0, r1), __fadd_rn(r2, r3));
        float rr = __fadd_rn(__fadd_rn(r4, r5), __fadd_rn(r6, r7));
        t1s = __fadd_rn(l, rr);
      }
      __syncthreads();
      float t1 = t1s;
      float best = 1e30f;
      int bi = 0;
      int e0 = threadIdx.x * 4;
      for (int e = e0; e < e0 + 4; ++e) {
        const float* E0 = Ef + e * DIM;
        double a = 0.0;
        for (int k = 0; k < DIM; ++k)
          a = fma((double)E0[k], (double)zs[k], a);
        float ahat = (float)a;
        float d = __fadd_rn(__fsub_rn(t1, __fmul_rn(2.0f, ahat)), ee[e]);
        if (d < best) { best = d; bi = e; }
      }
      bval[threadIdx.x] = best;
      bidx[threadIdx.x] = bi;
      __syncthreads();
      for (int s = 128; s > 0; s >>= 1) {
        if ((int)threadIdx.x < s) {
          float vb = bval[threadIdx.x + s];
          int ib = bidx[threadIdx.x + s];
          if (vb < bval[threadIdx.x] ||
              (vb == bval[threadIdx.x] && ib < bidx[threadIdx.x])) {
            bval[threadIdx.x] = vb;
            bidx[threadIdx.x] = ib;
          }
        }
        __syncthreads();
      }
      if (threadIdx.x == 0) idx[n] = bidx[0];
    }
  }
}

// ---- gather + idx-out + loss (atomic finalize; no separate k4) ----
__global__ __launch_bounds__(256) void k3_out(const void* __restrict__ zv,
                                              const float* __restrict__ ws,
                                              const int* __restrict__ idx,
                                              float* __restrict__ out,
                                              double* __restrict__ accD,
                                              int* __restrict__ cnt3) {
  int flag_z = ((const int*)ws)[FLAG_OFF] & 1;
  const float* Ef = ws + EMBF32_OFF;
  int g = blockIdx.x * 256 + threadIdx.x;   // 2048 blocks
  float acc = 0.f;
#pragma unroll
  for (int i = 0; i < 4; ++i) {
    int m = (g + i * 524288) * 4;
    int n = m >> 6, c = m & 63;
    f32x4 q = *(const f32x4*)&Ef[idx[n] * DIM + c];
    *(f32x4*)&out[m] = q;
    f32x4 zV;
    if (flag_z) {
      ushort4 zu = *(const ushort4*)((const unsigned short*)zv + m);
      zV[0] = b2f(zu.x); zV[1] = b2f(zu.y); zV[2] = b2f(zu.z); zV[3] = b2f(zu.w);
    } else {
      zV = *(const f32x4*)((const float*)zv + m);
    }
#pragma unroll
    for (int r = 0; r < 4; ++r) {
      float d = zV[r] - q[r];
      acc = __builtin_fmaf(d, d, acc);
    }
  }
  if (g < NPOS) out[(size_t)NELEM + 1 + g] = (float)idx[g];
  for (int off = 32; off > 0; off >>= 1) acc += __shfl_down(acc, off);
  __shared__ float ps[4];
  if ((threadIdx.x & 63) == 0) ps[threadIdx.x >> 6] = acc;
  __syncthreads();
  if (threadIdx.x == 0) {
    double p = (double)(ps[0] + ps[1] + ps[2] + ps[3]);
    atomicAdd(accD, p);
    __threadfence();
    int done = atomicAdd(cnt3, 1);
    if (done == (int)gridDim.x - 1) {
      double s = atomicAdd(accD, 0.0);   // atomic read of final sum
      out[NELEM] = (float)(1.25 * s / (double)NELEM);
    }
  }
}

extern "C" void kernel_launch(void* const* d_in, const int* in_sizes, int n_in,
                              void* d_out, int out_size, void* d_ws, size_t ws_size,
                              hipStream_t stream) {
  const void* z   = d_in[0];
  const void* emb = d_in[1];
  float* out = (float*)d_out;
  float* ws = (float*)d_ws;
  int* wsI = (int*)d_ws;
  int* idx  = wsI + IDX_OFF;
  int* cnt  = wsI + CNT_OFF;
  int* cnt2 = wsI + CNT2_OFF;
  int* cnt3 = wsI + CNT3_OFF;
  int* wl   = wsI + WL_OFF;
  int* wlp  = wsI + WLP_OFF;
  int* wl2  = wsI + WL2_OFF;
  double* accD = (double*)(wsI + ACC_OFF);

  hipLaunchKernelGGL(k_detect, dim3(1), dim3(64), 0, stream,
                     (const unsigned int*)z, (const unsigned int*)emb, wsI);
  hipLaunchKernelGGL(k0_prep, dim3(256), dim3(256), 0, stream, emb, ws);
  hipLaunchKernelGGL(k1_screen, dim3(NPOS / 128), dim3(256), 0, stream,
                     z, ws, idx, cnt, cnt2, wl, wlp, wl2);
  hipLaunchKernelGGL(k2_refine, dim3(384), dim3(256), 0, stream,
                     z, ws, cnt, cnt2, wl, wlp, wl2, idx);
  hipLaunchKernelGGL(k3_out, dim3(2048), dim3(256), 0, stream,
                     z, ws, idx, out, accD, cnt3);
}